// Round 1
// baseline (40.146 us; speedup 1.0000x reference)
//
#include <hip/hip_runtime.h>

constexpr int C = 26;              // 5*B + NUM_CLASS = 26 floats per cell
constexpr int MAIN_BLOCKS = 1024;
constexpr int MAIN_THREADS = 256;
constexpr float LAMBDA_LOC = 10.0f;
constexpr float LAMBDA_NOOBJ = 0.5f;

__device__ __forceinline__ float iou_f(float b1x, float b1y, float b1w, float b1h,
                                       float b2x, float b2y, float b2w, float b2h) {
    float cx1 = b1x * 64.f, cy1 = b1y * 64.f, hw1 = b1w * 224.f, hh1 = b1h * 224.f;
    float l1 = cx1 - hw1, t1 = cy1 - hh1, r1 = cx1 + hw1, bo1 = cy1 + hh1;
    float cx2 = b2x * 64.f, cy2 = b2y * 64.f, hw2 = b2w * 224.f, hh2 = b2h * 224.f;
    float l2 = cx2 - hw2, t2 = cy2 - hh2, r2 = cx2 + hw2, bo2 = cy2 + hh2;
    float xA = fmaxf(l1, l2), yA = fmaxf(t1, t2);
    float xB = fminf(r1, r2), yB = fminf(bo1, bo2);
    float iw = fmaxf(0.f, xB - xA + 1.f);
    float ih = fmaxf(0.f, yB - yA + 1.f);
    float inter = iw * ih;
    float a1 = (r1 - l1 + 1.f) * (bo1 - t1 + 1.f);
    float a2 = (r2 - l2 + 1.f) * (bo2 - t2 + 1.f);
    return inter / (a1 + a2 - inter);
}

__global__ __launch_bounds__(MAIN_THREADS) void yolo_main(
    const float* __restrict__ pred, const float* __restrict__ targ,
    float* __restrict__ partial, int rows)
{
    int gtid  = blockIdx.x * MAIN_THREADS + threadIdx.x;
    int gsize = gridDim.x * MAIN_THREADS;
    float acc = 0.f;

    for (int r = gtid; r < rows; r += gsize) {
        const float2* pr = reinterpret_cast<const float2*>(pred + (size_t)r * C);
        const float2* tr = reinterpret_cast<const float2*>(targ + (size_t)r * C);

        // elements 0..9 of both rows into registers (compile-time indices only)
        float2 p01 = pr[0], p23 = pr[1], p45 = pr[2], p67 = pr[3], p89 = pr[4];
        float2 t01 = tr[0], t23 = tr[1], t45 = tr[2], t67 = tr[3], t89 = tr[4];

        // class loss: elements 10..25
        float cls = 0.f;
        #pragma unroll
        for (int j = 5; j < 13; ++j) {
            float2 a = pr[j], b = tr[j];
            float dx = a.x - b.x, dy = a.y - b.y;
            cls = fmaf(dx, dx, cls);
            cls = fmaf(dy, dy, cls);
        }

        float obj   = t45.x;           // t[4]
        float noobj = 1.f - obj;

        // IOU of both predicted boxes vs target box t[0:4]
        float iou1 = iou_f(p01.x, p01.y, p23.x, p23.y, t01.x, t01.y, t23.x, t23.y);
        float iou2 = iou_f(p45.y, p67.x, p67.y, p89.x, t01.x, t01.y, t23.x, t23.y);

        bool  best2  = iou2 > iou1;
        float iou_m  = best2 ? iou2 : iou1;

        // vp = best2 ? p[5:10] : p[0:5]
        float vpx = best2 ? p45.y : p01.x;
        float vpy = best2 ? p67.x : p01.y;
        float vpw = best2 ? p67.y : p23.x;
        float vph = best2 ? p89.x : p23.y;
        float vpc = best2 ? p89.y : p45.x;
        // vt = best2 ? t[5:9] : t[0:4]
        float vtx = best2 ? t45.y : t01.x;
        float vty = best2 ? t67.x : t01.y;
        float vtw = best2 ? t67.y : t23.x;
        float vth = best2 ? t89.x : t23.y;

        float dx = vpx - vtx, dy = vpy - vty;
        float xy = dx * dx + dy * dy;
        float sw = sqrtf(vpw) - sqrtf(vtw);
        float sh = sqrtf(vph) - sqrtf(vth);
        float wh = sw * sw + sh * sh;
        float dc = vpc - iou_m;
        float oc = dc * dc;
        float d1 = p45.x - t45.x;    // p[4]-t[4]
        float d2 = p89.y - t89.y;    // p[9]-t[9]

        acc += obj * (LAMBDA_LOC * (xy + wh) + oc + 2.f * cls)
             + LAMBDA_NOOBJ * noobj * (d1 * d1 + d2 * d2);
    }

    // wave (64-lane) reduce
    #pragma unroll
    for (int off = 32; off > 0; off >>= 1)
        acc += __shfl_down(acc, off);

    __shared__ float wsum[MAIN_THREADS / 64];
    int lane = threadIdx.x & 63, wid = threadIdx.x >> 6;
    if (lane == 0) wsum[wid] = acc;
    __syncthreads();
    if (threadIdx.x == 0) {
        float s = 0.f;
        #pragma unroll
        for (int w = 0; w < MAIN_THREADS / 64; ++w) s += wsum[w];
        partial[blockIdx.x] = s;
    }
}

__global__ __launch_bounds__(256) void yolo_reduce(
    const float* __restrict__ partial, float* __restrict__ out, int n)
{
    float acc = 0.f;
    for (int i = threadIdx.x; i < n; i += 256) acc += partial[i];
    #pragma unroll
    for (int off = 32; off > 0; off >>= 1)
        acc += __shfl_down(acc, off);
    __shared__ float wsum[4];
    int lane = threadIdx.x & 63, wid = threadIdx.x >> 6;
    if (lane == 0) wsum[wid] = acc;
    __syncthreads();
    if (threadIdx.x == 0)
        out[0] = wsum[0] + wsum[1] + wsum[2] + wsum[3];
}

extern "C" void kernel_launch(void* const* d_in, const int* in_sizes, int n_in,
                              void* d_out, int out_size, void* d_ws, size_t ws_size,
                              hipStream_t stream) {
    const float* pred = (const float*)d_in[0];
    const float* targ = (const float*)d_in[1];
    float* out = (float*)d_out;
    float* partial = (float*)d_ws;   // MAIN_BLOCKS floats of scratch
    int rows = in_sizes[0] / C;      // 16384*7*7 = 802816

    yolo_main<<<MAIN_BLOCKS, MAIN_THREADS, 0, stream>>>(pred, targ, partial, rows);
    yolo_reduce<<<1, 256, 0, stream>>>(partial, out, MAIN_BLOCKS);
}

// Round 2
// 34.102 us; speedup vs baseline: 1.1772x; 1.1772x over previous
//
#include <hip/hip_runtime.h>

constexpr int C = 26;                 // floats per cell
constexpr int TILE_ROWS = 256;        // rows per block tile
constexpr int THREADS = 256;
constexpr int TILE_FLOATS = TILE_ROWS * C;          // 6656 floats = 26624 B
constexpr int TILE_F4 = TILE_FLOATS / 4;            // 1664 float4 chunks
constexpr float LAMBDA_LOC = 10.0f;
constexpr float LAMBDA_NOOBJ = 0.5f;

__device__ __forceinline__ void stage16(const float* g, float* lds_uniform) {
    // width-16 global->LDS: per-lane global src, wave-uniform LDS dst (+ HW lane*16)
    __builtin_amdgcn_global_load_lds(
        (const __attribute__((address_space(1))) unsigned int*)g,
        (__attribute__((address_space(3))) unsigned int*)lds_uniform,
        16, 0, 0);
}

__device__ __forceinline__ float iou_f(float b1x, float b1y, float b1w, float b1h,
                                       float b2x, float b2y, float b2w, float b2h) {
    float cx1 = b1x * 64.f, cy1 = b1y * 64.f, hw1 = b1w * 224.f, hh1 = b1h * 224.f;
    float l1 = cx1 - hw1, t1 = cy1 - hh1, r1 = cx1 + hw1, bo1 = cy1 + hh1;
    float cx2 = b2x * 64.f, cy2 = b2y * 64.f, hw2 = b2w * 224.f, hh2 = b2h * 224.f;
    float l2 = cx2 - hw2, t2 = cy2 - hh2, r2 = cx2 + hw2, bo2 = cy2 + hh2;
    float xA = fmaxf(l1, l2), yA = fmaxf(t1, t2);
    float xB = fminf(r1, r2), yB = fminf(bo1, bo2);
    float iw = fmaxf(0.f, xB - xA + 1.f);
    float ih = fmaxf(0.f, yB - yA + 1.f);
    float inter = iw * ih;
    float a1 = (r1 - l1 + 1.f) * (bo1 - t1 + 1.f);
    float a2 = (r2 - l2 + 1.f) * (bo2 - t2 + 1.f);
    return inter / (a1 + a2 - inter);
}

// rows MUST be a multiple of TILE_ROWS (802816 = 3136*256 here).
__global__ __launch_bounds__(THREADS) void yolo_main(
    const float* __restrict__ pred, const float* __restrict__ targ,
    float* __restrict__ partial)
{
    __shared__ float lds_p[TILE_FLOATS];
    __shared__ float lds_t[TILE_FLOATS];

    const int tid  = threadIdx.x;
    const int wid  = tid >> 6;                 // wave id 0..3
    const size_t tile_base = (size_t)blockIdx.x * TILE_FLOATS;
    const float* ptile = pred + tile_base;
    const float* ttile = targ + tile_base;

    // ---- stage tile: fully coalesced, 16B/lane, linear LDS ----
    #pragma unroll
    for (int k = 0; k < 6; ++k) {
        int j = k * 256 + tid;                 // float4 index within tile
        int u = (k * 256 + wid * 64) * 4;      // wave-uniform LDS float offset
        stage16(ptile + j * 4, lds_p + u);
        stage16(ttile + j * 4, lds_t + u);
    }
    if (wid < 2) {                             // j in [1536,1664): waves 0,1 only
        int j = 6 * 256 + tid;
        int u = (6 * 256 + wid * 64) * 4;
        stage16(ptile + j * 4, lds_p + u);
        stage16(ttile + j * 4, lds_t + u);
    }
    __syncthreads();                           // drains vmcnt (global_load_lds)

    // ---- per-thread row compute from LDS ----
    const float2* pr = reinterpret_cast<const float2*>(lds_p + tid * C);
    const float2* tr = reinterpret_cast<const float2*>(lds_t + tid * C);

    float2 p01 = pr[0], p23 = pr[1], p45 = pr[2], p67 = pr[3], p89 = pr[4];
    float2 t01 = tr[0], t23 = tr[1], t45 = tr[2], t67 = tr[3], t89 = tr[4];

    float cls = 0.f;
    #pragma unroll
    for (int j = 5; j < 13; ++j) {
        float2 a = pr[j], b = tr[j];
        float dx = a.x - b.x, dy = a.y - b.y;
        cls = fmaf(dx, dx, cls);
        cls = fmaf(dy, dy, cls);
    }

    float obj   = t45.x;
    float noobj = 1.f - obj;

    float iou1 = iou_f(p01.x, p01.y, p23.x, p23.y, t01.x, t01.y, t23.x, t23.y);
    float iou2 = iou_f(p45.y, p67.x, p67.y, p89.x, t01.x, t01.y, t23.x, t23.y);

    bool  best2 = iou2 > iou1;
    float iou_m = best2 ? iou2 : iou1;

    float vpx = best2 ? p45.y : p01.x;
    float vpy = best2 ? p67.x : p01.y;
    float vpw = best2 ? p67.y : p23.x;
    float vph = best2 ? p89.x : p23.y;
    float vpc = best2 ? p89.y : p45.x;
    float vtx = best2 ? t45.y : t01.x;
    float vty = best2 ? t67.x : t01.y;
    float vtw = best2 ? t67.y : t23.x;
    float vth = best2 ? t89.x : t23.y;

    float dx = vpx - vtx, dy = vpy - vty;
    float xy = dx * dx + dy * dy;
    float sw = sqrtf(vpw) - sqrtf(vtw);
    float sh = sqrtf(vph) - sqrtf(vth);
    float wh = sw * sw + sh * sh;
    float dc = vpc - iou_m;
    float oc = dc * dc;
    float d1 = p45.x - t45.x;
    float d2 = p89.y - t89.y;

    float acc = obj * (LAMBDA_LOC * (xy + wh) + oc + 2.f * cls)
              + LAMBDA_NOOBJ * noobj * (d1 * d1 + d2 * d2);

    // ---- block reduce ----
    #pragma unroll
    for (int off = 32; off > 0; off >>= 1)
        acc += __shfl_down(acc, off);

    __shared__ float wsum[THREADS / 64];
    int lane = tid & 63;
    if (lane == 0) wsum[wid] = acc;
    __syncthreads();
    if (tid == 0) {
        float s = 0.f;
        #pragma unroll
        for (int w = 0; w < THREADS / 64; ++w) s += wsum[w];
        partial[blockIdx.x] = s;
    }
}

__global__ __launch_bounds__(256) void yolo_reduce(
    const float* __restrict__ partial, float* __restrict__ out, int n)
{
    float acc = 0.f;
    for (int i = threadIdx.x; i < n; i += 256) acc += partial[i];
    #pragma unroll
    for (int off = 32; off > 0; off >>= 1)
        acc += __shfl_down(acc, off);
    __shared__ float wsum[4];
    int lane = threadIdx.x & 63, wid = threadIdx.x >> 6;
    if (lane == 0) wsum[wid] = acc;
    __syncthreads();
    if (threadIdx.x == 0)
        out[0] = wsum[0] + wsum[1] + wsum[2] + wsum[3];
}

extern "C" void kernel_launch(void* const* d_in, const int* in_sizes, int n_in,
                              void* d_out, int out_size, void* d_ws, size_t ws_size,
                              hipStream_t stream) {
    const float* pred = (const float*)d_in[0];
    const float* targ = (const float*)d_in[1];
    float* out = (float*)d_out;
    float* partial = (float*)d_ws;          // n_tiles floats of scratch
    int rows = in_sizes[0] / C;             // 802816
    int n_tiles = rows / TILE_ROWS;         // 3136 (exact)

    yolo_main<<<n_tiles, THREADS, 0, stream>>>(pred, targ, partial);
    yolo_reduce<<<1, 256, 0, stream>>>(partial, out, n_tiles);
}

// Round 3
// 33.139 us; speedup vs baseline: 1.2114x; 1.0291x over previous
//
#include <hip/hip_runtime.h>

constexpr int C = 26;                 // floats per cell
constexpr int TILE_ROWS = 128;        // rows per block tile
constexpr int THREADS = 256;
constexpr int TILE_FLOATS = TILE_ROWS * C;          // 3328 floats = 13312 B
constexpr float LAMBDA_LOC = 10.0f;
constexpr float LAMBDA_NOOBJ = 0.5f;

__device__ __forceinline__ void stage16(const float* g, float* lds_uniform) {
    // width-16 global->LDS: per-lane global src, wave-uniform LDS dst (+ HW lane*16)
    __builtin_amdgcn_global_load_lds(
        (const __attribute__((address_space(1))) unsigned int*)g,
        (__attribute__((address_space(3))) unsigned int*)lds_uniform,
        16, 0, 0);
}

__device__ __forceinline__ float iou_f(float b1x, float b1y, float b1w, float b1h,
                                       float b2x, float b2y, float b2w, float b2h) {
    float cx1 = b1x * 64.f, cy1 = b1y * 64.f, hw1 = b1w * 224.f, hh1 = b1h * 224.f;
    float l1 = cx1 - hw1, t1 = cy1 - hh1, r1 = cx1 + hw1, bo1 = cy1 + hh1;
    float cx2 = b2x * 64.f, cy2 = b2y * 64.f, hw2 = b2w * 224.f, hh2 = b2h * 224.f;
    float l2 = cx2 - hw2, t2 = cy2 - hh2, r2 = cx2 + hw2, bo2 = cy2 + hh2;
    float xA = fmaxf(l1, l2), yA = fmaxf(t1, t2);
    float xB = fminf(r1, r2), yB = fminf(bo1, bo2);
    float iw = fmaxf(0.f, xB - xA + 1.f);
    float ih = fmaxf(0.f, yB - yA + 1.f);
    float inter = iw * ih;
    float a1 = (r1 - l1 + 1.f) * (bo1 - t1 + 1.f);
    float a2 = (r2 - l2 + 1.f) * (bo2 - t2 + 1.f);
    return inter / (a1 + a2 - inter);
}

// rows MUST be a multiple of TILE_ROWS (802816 = 6272*128).
__global__ __launch_bounds__(THREADS, 6) void yolo_main(
    const float* __restrict__ pred, const float* __restrict__ targ,
    float* __restrict__ partial)
{
    __shared__ float lds_p[TILE_FLOATS];
    __shared__ float lds_t[TILE_FLOATS];

    const int tid  = threadIdx.x;
    const int wid  = tid >> 6;                 // wave id 0..3
    const size_t tile_base = (size_t)blockIdx.x * TILE_FLOATS;
    const float* ptile = pred + tile_base;
    const float* ttile = targ + tile_base;

    // ---- stage tile: fully coalesced, 16B/lane, linear LDS ----
    // 832 float4-chunks per input: k=0..2 full (768), tail 64 chunks -> wave 0.
    #pragma unroll
    for (int k = 0; k < 3; ++k) {
        int j = k * 256 + tid;                 // float4 index within tile
        int u = (k * 256 + wid * 64) * 4;      // wave-uniform LDS float offset
        stage16(ptile + j * 4, lds_p + u);
        stage16(ttile + j * 4, lds_t + u);
    }
    if (wid == 0) {                            // chunks [768,832): wave 0 only
        int j = 3 * 256 + tid;                 // tid in [0,64)
        int u = (3 * 256) * 4;
        stage16(ptile + j * 4, lds_p + u);
        stage16(ttile + j * 4, lds_t + u);
    }
    __syncthreads();                           // drains vmcnt (global_load_lds)

    // ---- per-thread row compute from LDS (threads 0..127 own rows) ----
    float acc = 0.f;
    if (tid < TILE_ROWS) {
        const float2* pr = reinterpret_cast<const float2*>(lds_p + tid * C);
        const float2* tr = reinterpret_cast<const float2*>(lds_t + tid * C);

        float2 p01 = pr[0], p23 = pr[1], p45 = pr[2], p67 = pr[3], p89 = pr[4];
        float2 t01 = tr[0], t23 = tr[1], t45 = tr[2], t67 = tr[3], t89 = tr[4];

        float cls = 0.f;
        #pragma unroll
        for (int j = 5; j < 13; ++j) {
            float2 a = pr[j], b = tr[j];
            float dx = a.x - b.x, dy = a.y - b.y;
            cls = fmaf(dx, dx, cls);
            cls = fmaf(dy, dy, cls);
        }

        float obj   = t45.x;
        float noobj = 1.f - obj;

        float iou1 = iou_f(p01.x, p01.y, p23.x, p23.y, t01.x, t01.y, t23.x, t23.y);
        float iou2 = iou_f(p45.y, p67.x, p67.y, p89.x, t01.x, t01.y, t23.x, t23.y);

        bool  best2 = iou2 > iou1;
        float iou_m = best2 ? iou2 : iou1;

        float vpx = best2 ? p45.y : p01.x;
        float vpy = best2 ? p67.x : p01.y;
        float vpw = best2 ? p67.y : p23.x;
        float vph = best2 ? p89.x : p23.y;
        float vpc = best2 ? p89.y : p45.x;
        float vtx = best2 ? t45.y : t01.x;
        float vty = best2 ? t67.x : t01.y;
        float vtw = best2 ? t67.y : t23.x;
        float vth = best2 ? t89.x : t23.y;

        float dx = vpx - vtx, dy = vpy - vty;
        float xy = dx * dx + dy * dy;
        float sw = sqrtf(vpw) - sqrtf(vtw);
        float sh = sqrtf(vph) - sqrtf(vth);
        float wh = sw * sw + sh * sh;
        float dc = vpc - iou_m;
        float oc = dc * dc;
        float d1 = p45.x - t45.x;
        float d2 = p89.y - t89.y;

        acc = obj * (LAMBDA_LOC * (xy + wh) + oc + 2.f * cls)
            + LAMBDA_NOOBJ * noobj * (d1 * d1 + d2 * d2);
    }

    // ---- block reduce (lanes without rows contribute 0) ----
    #pragma unroll
    for (int off = 32; off > 0; off >>= 1)
        acc += __shfl_down(acc, off);

    __shared__ float wsum[THREADS / 64];
    int lane = tid & 63;
    if (lane == 0) wsum[wid] = acc;
    __syncthreads();
    if (tid == 0) {
        float s = 0.f;
        #pragma unroll
        for (int w = 0; w < THREADS / 64; ++w) s += wsum[w];
        partial[blockIdx.x] = s;
    }
}

__global__ __launch_bounds__(1024) void yolo_reduce(
    const float* __restrict__ partial, float* __restrict__ out, int n)
{
    float acc = 0.f;
    for (int i = threadIdx.x; i < n; i += 1024) acc += partial[i];
    #pragma unroll
    for (int off = 32; off > 0; off >>= 1)
        acc += __shfl_down(acc, off);
    __shared__ float wsum[16];
    int lane = threadIdx.x & 63, wid = threadIdx.x >> 6;
    if (lane == 0) wsum[wid] = acc;
    __syncthreads();
    if (threadIdx.x == 0) {
        float s = 0.f;
        #pragma unroll
        for (int w = 0; w < 16; ++w) s += wsum[w];
        out[0] = s;
    }
}

extern "C" void kernel_launch(void* const* d_in, const int* in_sizes, int n_in,
                              void* d_out, int out_size, void* d_ws, size_t ws_size,
                              hipStream_t stream) {
    const float* pred = (const float*)d_in[0];
    const float* targ = (const float*)d_in[1];
    float* out = (float*)d_out;
    float* partial = (float*)d_ws;          // n_tiles floats of scratch
    int rows = in_sizes[0] / C;             // 802816
    int n_tiles = rows / TILE_ROWS;         // 6272 (exact)

    yolo_main<<<n_tiles, THREADS, 0, stream>>>(pred, targ, partial);
    yolo_reduce<<<1, 1024, 0, stream>>>(partial, out, n_tiles);
}